// Round 1
// baseline (1520.915 us; speedup 1.0000x reference)
//
#include <hip/hip_runtime.h>

#define BLK 256

// Read edge index `pos` from either an int64 or int32 edge buffer (wave-uniform flag).
__device__ __forceinline__ int edge_at(const void* idx, int is64, long long pos) {
  return is64 ? (int)((const long long*)idx)[pos] : ((const int*)idx)[pos];
}

// Detect int64 vs int32 storage: for int64 values < 2^31 the odd 32-bit words are 0.
__global__ void k_detect(const unsigned* __restrict__ w, int* __restrict__ flag) {
  __shared__ int any;
  if (threadIdx.x == 0) any = 0;
  __syncthreads();
  if (w[2 * threadIdx.x + 1] != 0u) atomicOr(&any, 1);
  __syncthreads();
  if (threadIdx.x == 0) *flag = (any == 0) ? 1 : 0;  // 1 => int64
}

__global__ void k_zero(float* __restrict__ p, int n) {
  int i = blockIdx.x * blockDim.x + threadIdx.x;
  if (i < n) p[i] = 0.0f;
}

__global__ void k_deg(const void* __restrict__ idx, const int* __restrict__ flag,
                      int E, int* __restrict__ deg) {
  int i = blockIdx.x * blockDim.x + threadIdx.x;
  if (i >= E) return;
  int is64 = *flag;
  int d = edge_at(idx, is64, (long long)E + i);
  atomicAdd(&deg[d], 1);
}

__global__ void k_prep(const float* __restrict__ x, const int* __restrict__ deg,
                       float* __restrict__ dinv, float* __restrict__ gx, int N) {
  int n = blockIdx.x * blockDim.x + threadIdx.x;
  if (n >= N) return;
  float di = rsqrtf((float)(deg[n] + 1));  // +1 self-loop; always > 0
  dinv[n] = di;
  gx[3 * n + 0] = di * x[3 * n + 0];
  gx[3 * n + 1] = di * x[3 * n + 1];
  gx[3 * n + 2] = di * x[3 * n + 2];
}

__global__ void k_scat1(const void* __restrict__ idx, const int* __restrict__ flag,
                        int E, const float* __restrict__ gx, float* __restrict__ aggx) {
  int i = blockIdx.x * blockDim.x + threadIdx.x;
  if (i >= E) return;
  int is64 = *flag;
  int s = edge_at(idx, is64, i);
  int d = edge_at(idx, is64, (long long)E + i);
  float v0 = gx[3 * s + 0], v1 = gx[3 * s + 1], v2 = gx[3 * s + 2];
  unsafeAtomicAdd(&aggx[3 * d + 0], v0);
  unsafeAtomicAdd(&aggx[3 * d + 1], v1);
  unsafeAtomicAdd(&aggx[3 * d + 2], v2);
}

__global__ void k_mid(const float* __restrict__ aggx, const float* __restrict__ gx,
                      const float* __restrict__ dinv,
                      const float* __restrict__ W1, const float* __restrict__ b1,
                      const float* __restrict__ W2,
                      float* __restrict__ g2, int N) {
  int n = blockIdx.x * blockDim.x + threadIdx.x;
  if (n >= N) return;
  float di = dinv[n];
  // layer-1 aggregated input (incl. self-loop term), pre-scaled by dinv[d]
  float a0 = (aggx[3 * n + 0] + gx[3 * n + 0]) * di;
  float a1 = (aggx[3 * n + 1] + gx[3 * n + 1]) * di;
  float a2 = (aggx[3 * n + 2] + gx[3 * n + 2]) * di;
  // fused: out1 = a @ W1 + b1 ; relu ; h2 = relu_out @ W2 ; g2 = dinv * h2
  float h2 = 0.0f;
#pragma unroll
  for (int k = 0; k < 16; ++k) {
    float o = fmaf(a0, W1[k], fmaf(a1, W1[16 + k], fmaf(a2, W1[32 + k], b1[k])));
    o = fmaxf(o, 0.0f);
    h2 = fmaf(o, W2[k], h2);
  }
  g2[n] = di * h2;
}

__global__ void k_scat2(const void* __restrict__ idx, const int* __restrict__ flag,
                        int E, const float* __restrict__ g2, float* __restrict__ agg2) {
  int i = blockIdx.x * blockDim.x + threadIdx.x;
  if (i >= E) return;
  int is64 = *flag;
  int s = edge_at(idx, is64, i);
  int d = edge_at(idx, is64, (long long)E + i);
  unsafeAtomicAdd(&agg2[d], g2[s]);
}

__global__ void k_final(const float* __restrict__ agg2, const float* __restrict__ g2,
                        const float* __restrict__ dinv, const float* __restrict__ b2,
                        float* __restrict__ out, int N) {
  int n = blockIdx.x * blockDim.x + threadIdx.x;
  if (n >= N) return;
  out[n] = dinv[n] * (agg2[n] + g2[n]) + b2[0];
}

extern "C" void kernel_launch(void* const* d_in, const int* in_sizes, int n_in,
                              void* d_out, int out_size, void* d_ws, size_t ws_size,
                              hipStream_t stream) {
  const float* x  = (const float*)d_in[0];
  const void*  ei = d_in[1];
  const float* W1 = (const float*)d_in[2];
  const float* b1 = (const float*)d_in[3];
  const float* W2 = (const float*)d_in[4];
  const float* b2 = (const float*)d_in[5];
  float* out = (float*)d_out;

  const int N = in_sizes[0] / 3;   // 200000
  const int E = in_sizes[1] / 2;   // 6400000

  // ws layout (bytes): [flag 256][deg N*4][aggx 3N*4][agg2 N*4][dinv N*4][gx 3N*4][g2 N*4]
  char* ws = (char*)d_ws;
  int*   flag = (int*)ws;
  int*   deg  = (int*)(ws + 256);
  float* aggx = (float*)(ws + 256 + 4ll * N);
  float* agg2 = (float*)(ws + 256 + 4ll * N * 4);
  float* dinv = (float*)(ws + 256 + 4ll * N * 5);
  float* gx   = (float*)(ws + 256 + 4ll * N * 6);
  float* g2   = (float*)(ws + 256 + 4ll * N * 9);

  int gE = (E + BLK - 1) / BLK;
  int gN = (N + BLK - 1) / BLK;
  int gZ = (5 * N + BLK - 1) / BLK;

  k_detect<<<1, 256, 0, stream>>>((const unsigned*)ei, flag);
  k_zero<<<gZ, BLK, 0, stream>>>((float*)deg, 5 * N);  // deg, aggx, agg2 are contiguous
  k_deg<<<gE, BLK, 0, stream>>>(ei, flag, E, deg);
  k_prep<<<gN, BLK, 0, stream>>>(x, deg, dinv, gx, N);
  k_scat1<<<gE, BLK, 0, stream>>>(ei, flag, E, gx, aggx);
  k_mid<<<gN, BLK, 0, stream>>>(aggx, gx, dinv, W1, b1, W2, g2, N);
  k_scat2<<<gE, BLK, 0, stream>>>(ei, flag, E, g2, agg2);
  k_final<<<gN, BLK, 0, stream>>>(agg2, g2, dinv, b2, out, N);
}

// Round 2
// 1338.343 us; speedup vs baseline: 1.1364x; 1.1364x over previous
//
#include <hip/hip_runtime.h>

#define BLK 256
#define PART_D 16000   // ints  -> 62.5 KB LDS (deg + layer-2 scatter)
#define PART_1 5000    // x3 floats -> 60 KB LDS (layer-1 scatter)

// ---------------- common helpers ----------------

__device__ __forceinline__ int edge_at(const void* idx, int is64, long long pos) {
  return is64 ? (int)((const long long*)idx)[pos] : ((const int*)idx)[pos];
}

// Detect int64 vs int32 storage: for int64 values < 2^31 the odd 32-bit words are 0.
__global__ void k_detect(const unsigned* __restrict__ w, int* __restrict__ flag) {
  __shared__ int any;
  if (threadIdx.x == 0) any = 0;
  __syncthreads();
  if (w[2 * threadIdx.x + 1] != 0u) atomicOr(&any, 1);
  __syncthreads();
  if (threadIdx.x == 0) *flag = (any == 0) ? 1 : 0;  // 1 => int64
}

__global__ void k_convert(const void* __restrict__ ei, const int* __restrict__ flag,
                          long long n, int* __restrict__ out32) {
  long long i = (long long)blockIdx.x * blockDim.x + threadIdx.x;
  if (i >= n) return;
  int is64 = *flag;
  out32[i] = is64 ? (int)((const long long*)ei)[i] : ((const int*)ei)[i];
}

// ---------------- partitioned (atomic-free) path ----------------

// degree histogram: grid (C, P), LDS int counters per node-partition
__global__ __launch_bounds__(512) void k_deg_part(const int* __restrict__ dst, int E, int N,
                                                  int chunk, int* __restrict__ partial) {
  __shared__ int cnt[PART_D];
  const int c = blockIdx.x, p = blockIdx.y;
  const int pstart = p * PART_D;
  const int psize = min(N - pstart, PART_D);
  for (int j = threadIdx.x; j < psize; j += blockDim.x) cnt[j] = 0;
  __syncthreads();
  const int beg = c * chunk, end = min(E, beg + chunk);
  const int nvec = (end - beg) & ~3;
  for (int i = beg + (int)threadIdx.x * 4; i < beg + nvec; i += (int)blockDim.x * 4) {
    int4 d4 = *(const int4*)(dst + i);
    unsigned u;
    u = (unsigned)(d4.x - pstart); if (u < (unsigned)psize) atomicAdd(&cnt[u], 1);
    u = (unsigned)(d4.y - pstart); if (u < (unsigned)psize) atomicAdd(&cnt[u], 1);
    u = (unsigned)(d4.z - pstart); if (u < (unsigned)psize) atomicAdd(&cnt[u], 1);
    u = (unsigned)(d4.w - pstart); if (u < (unsigned)psize) atomicAdd(&cnt[u], 1);
  }
  for (int i = beg + nvec + threadIdx.x; i < end; i += blockDim.x) {
    unsigned u = (unsigned)(dst[i] - pstart);
    if (u < (unsigned)psize) atomicAdd(&cnt[u], 1);
  }
  __syncthreads();
  int* out = partial + (size_t)c * N + pstart;
  for (int j = threadIdx.x; j < psize; j += blockDim.x) out[j] = cnt[j];
}

// reduce deg partials -> dinv, gx = dinv * x
__global__ void k_prep_part(const int* __restrict__ partialD, int C, int N,
                            const float* __restrict__ x,
                            float* __restrict__ dinv, float* __restrict__ gx) {
  int n = blockIdx.x * blockDim.x + threadIdx.x;
  if (n >= N) return;
  int deg = 1;  // self-loop
  for (int c = 0; c < C; ++c) deg += partialD[(size_t)c * N + n];
  float di = rsqrtf((float)deg);
  dinv[n] = di;
  gx[3 * n + 0] = di * x[3 * n + 0];
  gx[3 * n + 1] = di * x[3 * n + 1];
  gx[3 * n + 2] = di * x[3 * n + 2];
}

// layer-1 scatter: accumulate gx[src] (3 floats) into LDS partition of dst
__global__ __launch_bounds__(512) void k_scat1_part(const int* __restrict__ src,
                                                    const int* __restrict__ dst,
                                                    int E, int N, int chunk,
                                                    const float* __restrict__ gx,
                                                    float* __restrict__ partial) {
  __shared__ float acc[3 * PART_1];
  const int c = blockIdx.x, p = blockIdx.y;
  const int pstart = p * PART_1;
  const int psize = min(N - pstart, PART_1);
  for (int j = threadIdx.x; j < 3 * psize; j += blockDim.x) acc[j] = 0.0f;
  __syncthreads();
  const int beg = c * chunk, end = min(E, beg + chunk);
  const int nvec = (end - beg) & ~3;
  for (int i = beg + (int)threadIdx.x * 4; i < beg + nvec; i += (int)blockDim.x * 4) {
    int4 d4 = *(const int4*)(dst + i);
    int dd[4] = {d4.x, d4.y, d4.z, d4.w};
#pragma unroll
    for (int j = 0; j < 4; ++j) {
      unsigned u = (unsigned)(dd[j] - pstart);
      if (u < (unsigned)psize) {
        int s = src[i + j];
        atomicAdd(&acc[3 * u + 0], gx[3 * s + 0]);
        atomicAdd(&acc[3 * u + 1], gx[3 * s + 1]);
        atomicAdd(&acc[3 * u + 2], gx[3 * s + 2]);
      }
    }
  }
  for (int i = beg + nvec + threadIdx.x; i < end; i += blockDim.x) {
    unsigned u = (unsigned)(dst[i] - pstart);
    if (u < (unsigned)psize) {
      int s = src[i];
      atomicAdd(&acc[3 * u + 0], gx[3 * s + 0]);
      atomicAdd(&acc[3 * u + 1], gx[3 * s + 1]);
      atomicAdd(&acc[3 * u + 2], gx[3 * s + 2]);
    }
  }
  __syncthreads();
  float* out = partial + (size_t)c * 3 * N + 3 * pstart;
  for (int j = threadIdx.x; j < 3 * psize; j += blockDim.x) out[j] = acc[j];
}

// reduce layer-1 partials + self-loop, fused W1+b1+relu+W2 -> g2
__global__ void k_mid_part(const float* __restrict__ partial, int C, int N,
                           const float* __restrict__ gx, const float* __restrict__ dinv,
                           const float* __restrict__ W1, const float* __restrict__ b1,
                           const float* __restrict__ W2, float* __restrict__ g2) {
  int n = blockIdx.x * blockDim.x + threadIdx.x;
  if (n >= N) return;
  float a0 = gx[3 * n + 0], a1 = gx[3 * n + 1], a2 = gx[3 * n + 2];  // self-loop
  for (int c = 0; c < C; ++c) {
    const float* pp = partial + (size_t)c * 3 * N + 3 * n;
    a0 += pp[0]; a1 += pp[1]; a2 += pp[2];
  }
  float di = dinv[n];
  a0 *= di; a1 *= di; a2 *= di;
  float h2 = 0.0f;
#pragma unroll
  for (int k = 0; k < 16; ++k) {
    float o = fmaf(a0, W1[k], fmaf(a1, W1[16 + k], fmaf(a2, W1[32 + k], b1[k])));
    o = fmaxf(o, 0.0f);
    h2 = fmaf(o, W2[k], h2);
  }
  g2[n] = di * h2;
}

// layer-2 scatter: accumulate scalar g2[src] into LDS partition of dst
__global__ __launch_bounds__(512) void k_scat2_part(const int* __restrict__ src,
                                                    const int* __restrict__ dst,
                                                    int E, int N, int chunk,
                                                    const float* __restrict__ g2,
                                                    float* __restrict__ partial) {
  __shared__ float acc[PART_D];
  const int c = blockIdx.x, p = blockIdx.y;
  const int pstart = p * PART_D;
  const int psize = min(N - pstart, PART_D);
  for (int j = threadIdx.x; j < psize; j += blockDim.x) acc[j] = 0.0f;
  __syncthreads();
  const int beg = c * chunk, end = min(E, beg + chunk);
  const int nvec = (end - beg) & ~3;
  for (int i = beg + (int)threadIdx.x * 4; i < beg + nvec; i += (int)blockDim.x * 4) {
    int4 d4 = *(const int4*)(dst + i);
    int dd[4] = {d4.x, d4.y, d4.z, d4.w};
#pragma unroll
    for (int j = 0; j < 4; ++j) {
      unsigned u = (unsigned)(dd[j] - pstart);
      if (u < (unsigned)psize) atomicAdd(&acc[u], g2[src[i + j]]);
    }
  }
  for (int i = beg + nvec + threadIdx.x; i < end; i += blockDim.x) {
    unsigned u = (unsigned)(dst[i] - pstart);
    if (u < (unsigned)psize) atomicAdd(&acc[u], g2[src[i]]);
  }
  __syncthreads();
  float* out = partial + (size_t)c * N + pstart;
  for (int j = threadIdx.x; j < psize; j += blockDim.x) out[j] = acc[j];
}

// reduce layer-2 partials + self-loop + bias -> out
__global__ void k_final_part(const float* __restrict__ partial, int C, int N,
                             const float* __restrict__ g2, const float* __restrict__ dinv,
                             const float* __restrict__ b2, float* __restrict__ out) {
  int n = blockIdx.x * blockDim.x + threadIdx.x;
  if (n >= N) return;
  float s = g2[n];  // self-loop
  for (int c = 0; c < C; ++c) s += partial[(size_t)c * N + n];
  out[n] = dinv[n] * s + b2[0];
}

// ---------------- fallback (round-1 atomic) path ----------------

__global__ void k_zero(float* __restrict__ p, int n) {
  int i = blockIdx.x * blockDim.x + threadIdx.x;
  if (i < n) p[i] = 0.0f;
}

__global__ void k_deg(const void* __restrict__ idx, const int* __restrict__ flag,
                      int E, int* __restrict__ deg) {
  int i = blockIdx.x * blockDim.x + threadIdx.x;
  if (i >= E) return;
  int is64 = *flag;
  atomicAdd(&deg[edge_at(idx, is64, (long long)E + i)], 1);
}

__global__ void k_prep(const float* __restrict__ x, const int* __restrict__ deg,
                       float* __restrict__ dinv, float* __restrict__ gx, int N) {
  int n = blockIdx.x * blockDim.x + threadIdx.x;
  if (n >= N) return;
  float di = rsqrtf((float)(deg[n] + 1));
  dinv[n] = di;
  gx[3 * n + 0] = di * x[3 * n + 0];
  gx[3 * n + 1] = di * x[3 * n + 1];
  gx[3 * n + 2] = di * x[3 * n + 2];
}

__global__ void k_scat1(const void* __restrict__ idx, const int* __restrict__ flag,
                        int E, const float* __restrict__ gx, float* __restrict__ aggx) {
  int i = blockIdx.x * blockDim.x + threadIdx.x;
  if (i >= E) return;
  int is64 = *flag;
  int s = edge_at(idx, is64, i);
  int d = edge_at(idx, is64, (long long)E + i);
  unsafeAtomicAdd(&aggx[3 * d + 0], gx[3 * s + 0]);
  unsafeAtomicAdd(&aggx[3 * d + 1], gx[3 * s + 1]);
  unsafeAtomicAdd(&aggx[3 * d + 2], gx[3 * s + 2]);
}

__global__ void k_mid(const float* __restrict__ aggx, const float* __restrict__ gx,
                      const float* __restrict__ dinv,
                      const float* __restrict__ W1, const float* __restrict__ b1,
                      const float* __restrict__ W2, float* __restrict__ g2, int N) {
  int n = blockIdx.x * blockDim.x + threadIdx.x;
  if (n >= N) return;
  float di = dinv[n];
  float a0 = (aggx[3 * n + 0] + gx[3 * n + 0]) * di;
  float a1 = (aggx[3 * n + 1] + gx[3 * n + 1]) * di;
  float a2 = (aggx[3 * n + 2] + gx[3 * n + 2]) * di;
  float h2 = 0.0f;
#pragma unroll
  for (int k = 0; k < 16; ++k) {
    float o = fmaf(a0, W1[k], fmaf(a1, W1[16 + k], fmaf(a2, W1[32 + k], b1[k])));
    o = fmaxf(o, 0.0f);
    h2 = fmaf(o, W2[k], h2);
  }
  g2[n] = di * h2;
}

__global__ void k_scat2(const void* __restrict__ idx, const int* __restrict__ flag,
                        int E, const float* __restrict__ g2, float* __restrict__ agg2) {
  int i = blockIdx.x * blockDim.x + threadIdx.x;
  if (i >= E) return;
  int is64 = *flag;
  int s = edge_at(idx, is64, i);
  int d = edge_at(idx, is64, (long long)E + i);
  unsafeAtomicAdd(&agg2[d], g2[s]);
}

__global__ void k_final(const float* __restrict__ agg2, const float* __restrict__ g2,
                        const float* __restrict__ dinv, const float* __restrict__ b2,
                        float* __restrict__ out, int N) {
  int n = blockIdx.x * blockDim.x + threadIdx.x;
  if (n >= N) return;
  out[n] = dinv[n] * (agg2[n] + g2[n]) + b2[0];
}

// ---------------- launch ----------------

extern "C" void kernel_launch(void* const* d_in, const int* in_sizes, int n_in,
                              void* d_out, int out_size, void* d_ws, size_t ws_size,
                              hipStream_t stream) {
  const float* x  = (const float*)d_in[0];
  const void*  ei = d_in[1];
  const float* W1 = (const float*)d_in[2];
  const float* b1 = (const float*)d_in[3];
  const float* W2 = (const float*)d_in[4];
  const float* b2 = (const float*)d_in[5];
  float* out = (float*)d_out;

  const int N = in_sizes[0] / 3;   // 200000
  const int E = in_sizes[1] / 2;   // 6400000

  char* ws = (char*)d_ws;
  int* flag = (int*)ws;

  // partitioned-path layout
  int*   es32   = (int*)(ws + 256);                      // [2E]
  float* dinv_p = (float*)(ws + 256 + (size_t)2 * E * 4);
  float* gx_p   = dinv_p + N;                            // [3N]
  float* g2_p   = gx_p + 3 * (size_t)N;                  // [N]
  float* partial = g2_p + N;                             // shared partial region

  size_t fixed = 256 + (size_t)2 * E * 4 + (size_t)5 * N * 4;
  size_t avail = ws_size > fixed ? ws_size - fixed : 0;
  int C1 = (int)((avail / ((size_t)3 * N * 4)) < 13 ? (avail / ((size_t)3 * N * 4)) : 13);
  int CD = (int)((avail / ((size_t)N * 4)) < 20 ? (avail / ((size_t)N * 4)) : 20);

  int gN = (N + BLK - 1) / BLK;

  if (C1 >= 2) {
    // ---- atomic-free partitioned path ----
    const int P_D = (N + PART_D - 1) / PART_D;  // 13
    const int P_1 = (N + PART_1 - 1) / PART_1;  // 40
    int chunkD = (((E + CD - 1) / CD) + 3) & ~3;
    int chunk1 = (((E + C1 - 1) / C1) + 3) & ~3;

    k_detect<<<1, 256, 0, stream>>>((const unsigned*)ei, flag);
    k_convert<<<(int)((2LL * E + BLK - 1) / BLK), BLK, 0, stream>>>(ei, flag, 2LL * E, es32);
    const int* src32 = es32;
    const int* dst32 = es32 + E;

    k_deg_part<<<dim3(CD, P_D), 512, 0, stream>>>(dst32, E, N, chunkD, (int*)partial);
    k_prep_part<<<gN, BLK, 0, stream>>>((const int*)partial, CD, N, x, dinv_p, gx_p);
    k_scat1_part<<<dim3(C1, P_1), 512, 0, stream>>>(src32, dst32, E, N, chunk1, gx_p, partial);
    k_mid_part<<<gN, BLK, 0, stream>>>(partial, C1, N, gx_p, dinv_p, W1, b1, W2, g2_p);
    k_scat2_part<<<dim3(CD, P_D), 512, 0, stream>>>(src32, dst32, E, N, chunkD, g2_p, partial);
    k_final_part<<<gN, BLK, 0, stream>>>(partial, CD, N, g2_p, dinv_p, b2, out);
  } else {
    // ---- fallback: round-1 atomic path (ws layout as round 1) ----
    int*   deg  = (int*)(ws + 256);
    float* aggx = (float*)(ws + 256 + 4ll * N);
    float* agg2 = (float*)(ws + 256 + 4ll * N * 4);
    float* dinv = (float*)(ws + 256 + 4ll * N * 5);
    float* gx   = (float*)(ws + 256 + 4ll * N * 6);
    float* g2   = (float*)(ws + 256 + 4ll * N * 9);

    int gE = (E + BLK - 1) / BLK;
    int gZ = (5 * N + BLK - 1) / BLK;

    k_detect<<<1, 256, 0, stream>>>((const unsigned*)ei, flag);
    k_zero<<<gZ, BLK, 0, stream>>>((float*)deg, 5 * N);
    k_deg<<<gE, BLK, 0, stream>>>(ei, flag, E, deg);
    k_prep<<<gN, BLK, 0, stream>>>(x, deg, dinv, gx, N);
    k_scat1<<<gE, BLK, 0, stream>>>(ei, flag, E, gx, aggx);
    k_mid<<<gN, BLK, 0, stream>>>(aggx, gx, dinv, W1, b1, W2, g2, N);
    k_scat2<<<gE, BLK, 0, stream>>>(ei, flag, E, g2, agg2);
    k_final<<<gN, BLK, 0, stream>>>(agg2, g2, dinv, b2, out, N);
  }
}